// Round 19
// baseline (247.860 us; speedup 1.0000x reference)
//
#include <hip/hip_runtime.h>

// KCenterSampler FPS — paired-step speculation over the proven LLC exchange.
//
// Exchange slot (per block, 32B): {ka, kb, kc} u64 keys + pad.
//   kc = top-1 after the CERTAIN update (center w = far_{s-1})
//   ka,kb = top-2 after the SPECULATIVE update (centers w then c)
// far_s = max kc. If far_s's key == c's key (bit-exact, index+value), the
// speculative state is exact: commit it, far_{s+1} = max ka, next spec =
// global #2 of {ka,kb} — TWO steps per LLC round-trip. Else: rollback
// (committed df kept separately) + one normal exchange (baseline cost).
// Keys pack (monotone(dist), NPTS-j): max == first-index-tie-break argmax,
// so all order decisions are bit-exact vs the reference. All blocks compute
// branches from identical exchanged data -> lockstep; every block publishes
// every row it polls (write-once, memset-zeroed) -> no deadlock.
//
// Retained proven pieces: agent-scope RELAXED u64 slot channel + depth-3
// pipelined poll (R12/R17), bid&7 XCD co-location, coords/sq/dist in VGPRs
// (waves_per_eu(1,1) + asm launder), DPP reductions, fused gather (wave 1).
// Arithmetic bit-identical to R1/3/4/8/9/12/13/17 (absmax 0).

#define NPTS 6272
#define CDIM 35
#define BT   8
#define KSEL 128
#define THW  12544
#define BPS  16                  // blocks per segment
#define PPB  392                 // points per block
#define BLK  256
#define NB   (BT * BPS)          // 128 blocks
#define TAILN (PPB - BLK)        // 136: threads owning a 2nd point
#define ROWS 128                 // exchange rows per segment (max 127 used)

__device__ __forceinline__ unsigned long long key_of(float v, int j) {
  unsigned int u = __float_as_uint(v);
  u = (u & 0x80000000u) ? ~u : (u | 0x80000000u);   // monotone float->uint
  return ((unsigned long long)u << 32) | (unsigned int)(NPTS - j); // both words !=0
}
__device__ __forceinline__ unsigned long long kmax(unsigned long long a,
                                                   unsigned long long b) {
  return a > b ? a : b;
}
__device__ __forceinline__ unsigned long long kmin(unsigned long long a,
                                                   unsigned long long b) {
  return a < b ? a : b;
}

struct KPair { unsigned long long b, s; };   // top-2 (best, second)
__device__ __forceinline__ KPair pmerge(KPair x, KPair y) {
  KPair r;
  r.b = kmax(x.b, y.b);
  r.s = kmax(kmin(x.b, y.b), kmax(x.s, y.s));
  return r;
}

template <int CTRL, int RMASK, bool BC>
__device__ __forceinline__ unsigned long long dpp_mov64(unsigned long long k) {
  unsigned int lo = (unsigned int)k, hi = (unsigned int)(k >> 32);
  unsigned int tlo = (unsigned int)__builtin_amdgcn_update_dpp(0, (int)lo, CTRL, RMASK, 0xF, BC);
  unsigned int thi = (unsigned int)__builtin_amdgcn_update_dpp(0, (int)hi, CTRL, RMASK, 0xF, BC);
  return ((unsigned long long)thi << 32) | tlo;
}
template <int CTRL, int RMASK, bool BC>
__device__ __forceinline__ unsigned long long dpp_kmax(unsigned long long k) {
  return kmax(k, dpp_mov64<CTRL, RMASK, BC>(k));
}
template <int CTRL, int RMASK, bool BC>
__device__ __forceinline__ KPair dpp_pmerge(KPair p) {
  KPair t;
  t.b = dpp_mov64<CTRL, RMASK, BC>(p.b);
  t.s = dpp_mov64<CTRL, RMASK, BC>(p.s);
  return pmerge(p, t);
}
// 64-lane reduce networks (disjoint windows; result lane 63, broadcast back)
__device__ __forceinline__ unsigned long long wave_kmax64(unsigned long long k) {
  k = dpp_kmax<0x111, 0xF, true >(k);
  k = dpp_kmax<0x112, 0xF, true >(k);
  k = dpp_kmax<0x114, 0xF, true >(k);
  k = dpp_kmax<0x118, 0xF, true >(k);
  k = dpp_kmax<0x142, 0xA, false>(k);
  k = dpp_kmax<0x143, 0xC, false>(k);
  unsigned int rlo = (unsigned int)__builtin_amdgcn_readlane((int)(unsigned int)k, 63);
  unsigned int rhi = (unsigned int)__builtin_amdgcn_readlane((int)(k >> 32), 63);
  return ((unsigned long long)rhi << 32) | rlo;
}
__device__ __forceinline__ KPair wave_preduce(KPair p) {
  p = dpp_pmerge<0x111, 0xF, true >(p);
  p = dpp_pmerge<0x112, 0xF, true >(p);
  p = dpp_pmerge<0x114, 0xF, true >(p);
  p = dpp_pmerge<0x118, 0xF, true >(p);
  p = dpp_pmerge<0x142, 0xA, false>(p);
  p = dpp_pmerge<0x143, 0xC, false>(p);
  unsigned int blo = (unsigned int)__builtin_amdgcn_readlane((int)(unsigned int)p.b, 63);
  unsigned int bhi = (unsigned int)__builtin_amdgcn_readlane((int)(p.b >> 32), 63);
  unsigned int slo = (unsigned int)__builtin_amdgcn_readlane((int)(unsigned int)p.s, 63);
  unsigned int shi = (unsigned int)__builtin_amdgcn_readlane((int)(p.s >> 32), 63);
  KPair r;
  r.b = ((unsigned long long)bhi << 32) | blo;
  r.s = ((unsigned long long)shi << 32) | slo;
  return r;
}

// depth-3 pipelined LLC poll of one u64 slot (write-once 0->key) — R17-proven.
__device__ __forceinline__ unsigned long long poll_slot(const unsigned long long* p) {
  unsigned int klo = 0u, khi = 0u;
  unsigned int a0, b0, a1, b1, a2, b2, t;
  asm volatile(
      "global_load_dword %[a0], %[ad], off sc0 sc1\n\t"
      "global_load_dword %[b0], %[ad], off offset:4 sc0 sc1\n\t"
      "global_load_dword %[a1], %[ad], off sc0 sc1\n\t"
      "global_load_dword %[b1], %[ad], off offset:4 sc0 sc1\n\t"
      "global_load_dword %[a2], %[ad], off sc0 sc1\n\t"
      "global_load_dword %[b2], %[ad], off offset:4 sc0 sc1\n\t"
      "1:\n\t"
      "s_waitcnt vmcnt(4)\n\t"
      "v_max_u32 %[klo], %[klo], %[a0]\n\t"
      "v_max_u32 %[khi], %[khi], %[b0]\n\t"
      "global_load_dword %[a0], %[ad], off sc0 sc1\n\t"
      "global_load_dword %[b0], %[ad], off offset:4 sc0 sc1\n\t"
      "v_min_u32 %[t], %[klo], %[khi]\n\t"
      "v_cmp_eq_u32 vcc, 0, %[t]\n\t"
      "s_cbranch_vccz 9f\n\t"
      "s_waitcnt vmcnt(4)\n\t"
      "v_max_u32 %[klo], %[klo], %[a1]\n\t"
      "v_max_u32 %[khi], %[khi], %[b1]\n\t"
      "global_load_dword %[a1], %[ad], off sc0 sc1\n\t"
      "global_load_dword %[b1], %[ad], off offset:4 sc0 sc1\n\t"
      "v_min_u32 %[t], %[klo], %[khi]\n\t"
      "v_cmp_eq_u32 vcc, 0, %[t]\n\t"
      "s_cbranch_vccz 9f\n\t"
      "s_waitcnt vmcnt(4)\n\t"
      "v_max_u32 %[klo], %[klo], %[a2]\n\t"
      "v_max_u32 %[khi], %[khi], %[b2]\n\t"
      "global_load_dword %[a2], %[ad], off sc0 sc1\n\t"
      "global_load_dword %[b2], %[ad], off offset:4 sc0 sc1\n\t"
      "v_min_u32 %[t], %[klo], %[khi]\n\t"
      "v_cmp_eq_u32 vcc, 0, %[t]\n\t"
      "s_cbranch_vccnz 1b\n\t"
      "9:\n\t"
      "s_waitcnt vmcnt(0)"
      : [klo] "+v"(klo), [khi] "+v"(khi),
        [a0] "=&v"(a0), [b0] "=&v"(b0), [a1] "=&v"(a1), [b1] "=&v"(b1),
        [a2] "=&v"(a2), [b2] "=&v"(b2), [t] "=&v"(t)
      : [ad] "v"(p)
      : "vcc", "memory");
  return ((unsigned long long)khi << 32) | klo;
}

struct ExRes { unsigned long long maxkc, g1, g2; };

// one exchange: wave reduces -> block combine -> publish {P.b,P.s,KC} ->
// wave-0 48-lane poll -> global reduces -> broadcast via LDS.
__device__ __forceinline__ ExRes do_exchange(
    unsigned long long* seg, int row, KPair pp, unsigned long long kk,
    int sub, int tid, int lane, int wid,
    unsigned long long* wk, unsigned long long* wb, unsigned long long* wsec,
    unsigned long long* res) {
  unsigned long long kcw = wave_kmax64(kk);
  KPair pw = wave_preduce(pp);
  if (lane == 0) { wk[wid] = kcw; wb[wid] = pw.b; wsec[wid] = pw.s; }
  __syncthreads();                                       // barrier 1
  if (tid == 0) {
    unsigned long long KC = kmax(kmax(wk[0], wk[1]), kmax(wk[2], wk[3]));
    KPair P0{wb[0], wsec[0]}, P1{wb[1], wsec[1]}, P2{wb[2], wsec[2]}, P3{wb[3], wsec[3]};
    KPair P = pmerge(pmerge(P0, P1), pmerge(P2, P3));
    unsigned long long* slot = seg + (size_t)row * 64 + sub * 4;
    __hip_atomic_store(slot + 0, P.b, __ATOMIC_RELAXED, __HIP_MEMORY_SCOPE_AGENT);
    __hip_atomic_store(slot + 1, P.s, __ATOMIC_RELAXED, __HIP_MEMORY_SCOPE_AGENT);
    __hip_atomic_store(slot + 2, KC,  __ATOMIC_RELAXED, __HIP_MEMORY_SCOPE_AGENT);
  }
  asm volatile("" ::: "memory");
  if (wid == 0) {
    unsigned long long kv = 0ull;
    if (lane < 48)
      kv = poll_slot(seg + (size_t)row * 64 + (lane & 15) * 4 + (lane >> 4));
    unsigned long long kcv = (lane >= 32) ? kv : 0ull;   // lanes 32-47 hold kc
    kcv = wave_kmax64(kcv);
    KPair q{(lane < 32) ? kv : 0ull, 0ull};              // lanes 0-31: ka,kb
    q = wave_preduce(q);
    if (lane == 0) { res[0] = kcv; res[1] = q.b; res[2] = q.s; }
  }
  __syncthreads();                                       // barrier 2
  ExRes r;
  r.maxkc = res[0]; r.g1 = res[1]; r.g2 = res[2];
  return r;
}

__device__ __forceinline__ int key_idx(unsigned long long k) {
  return NPTS - (int)(unsigned int)(k & 0xFFFFFFFFull);
}

__global__ __attribute__((amdgpu_waves_per_eu(1, 1))) __launch_bounds__(BLK)
void fps_kernel(const float* __restrict__ x,
                const int* __restrict__ init_,
                float* __restrict__ patches,
                float* __restrict__ sidx,
                unsigned long long* __restrict__ slots) {
  __shared__ unsigned long long wk[4], wb[4], wsec[4], res[3];

  const int bid  = (int)blockIdx.x;
  const int b    = bid & 7;            // segment: round-robin -> same XCD
  const int sub  = bid >> 3;           // sub-block 0..15
  const int tid  = (int)threadIdx.x;
  const int lane = tid & 63;
  const int wid  = tid >> 6;
  const int j0t  = sub * PPB + tid;            // owned point 0
  const int j1t  = sub * PPB + BLK + tid;      // owned point 1 (tid<TAILN)
  const int td   = b & 1;
  const float* xg = x + (size_t)b * NPTS * CDIM;
  unsigned long long* seg = slots + (size_t)b * ROWS * 64;

  // ---- one-time load: coords -> VGPRs (laundered), sq sequential ----
  float xr0[CDIM], xr1[CDIM];
  float sqr0, sqr1, df0, df1;
  {
    const float* src0 = xg + (size_t)j0t * CDIM;
    float acc = 0.0f;
    {
#pragma clang fp contract(off)
#pragma unroll
      for (int c = 0; c < CDIM; ++c) { float v = src0[c]; xr0[c] = v; acc = acc + v * v; }
    }
    sqr0 = acc; df0 = 50000.0f;
    sqr1 = 0.0f; df1 = 50000.0f;
#pragma unroll
    for (int c = 0; c < CDIM; ++c) xr1[c] = 0.0f;
    if (tid < TAILN) {
      const float* src1 = xg + (size_t)j1t * CDIM;
      float acc1 = 0.0f;
      {
#pragma clang fp contract(off)
#pragma unroll
        for (int c = 0; c < CDIM; ++c) { float v = src1[c]; xr1[c] = v; acc1 = acc1 + v * v; }
      }
      sqr1 = acc1;
    }
#pragma unroll
    for (int c = 0; c < CDIM; ++c) {
      asm volatile("" : "+v"(xr0[c]));
      asm volatile("" : "+v"(xr1[c]));
    }
    asm volatile("" : "+v"(sqr0));
    asm volatile("" : "+v"(sqr1));
  }

  int w;                                // certain center (not yet applied)
  { int f = init_[b] % NPTS; if (f < 0) f += NPTS; w = f; }   // far_0
  if (sub == 0 && wid == 1) {           // output row 0
    if (lane == 0) sidx[b * KSEL] = (float)(w + td * NPTS);
    if (lane < 32) patches[(size_t)(b * KSEL) * 32 + lane] = xg[(size_t)w * CDIM + lane];
  }

  unsigned long long cK = 0;            // speculative center's key
  int cidx = 0;
  int row = 0;

// ---- macro: one certain update pass with center CEN (xf/sqf given) ----
#define CERTAIN_TAIL(SQF, DW0, DW1, CEN)                                   \
  {                                                                        \
    float d2a;                                                             \
    { _Pragma("clang fp contract(off)") d2a = (SQF + sqr0) - 2.0f * DW0; } \
    d2a = fmaxf(d2a, 0.0f);                                                \
    float da = __fsqrt_rn(d2a);                                            \
    da = (j0t == (CEN)) ? -1.0f : da;                                      \
    df0 = fminf(da, df0);                                                  \
    if (tid < TAILN) {                                                     \
      float d2b;                                                           \
      { _Pragma("clang fp contract(off)") d2b = (SQF + sqr1) - 2.0f * DW1; } \
      d2b = fmaxf(d2b, 0.0f);                                              \
      float db = __fsqrt_rn(d2b);                                          \
      db = (j1t == (CEN)) ? -1.0f : db;                                    \
      df1 = fminf(db, df1);                                                \
    }                                                                      \
  }

  // ---- X0: certain pass with far_0, top-2 exchange (row 0) ----
  {
    const int wu = __builtin_amdgcn_readfirstlane(w);
    const float* fx = xg + (size_t)wu * CDIM;
    float xfw[CDIM];
#pragma unroll
    for (int c = 0; c < CDIM; ++c) xfw[c] = fx[c];
    float sqfw;
    {
#pragma clang fp contract(off)
      float a = 0.0f;
#pragma unroll
      for (int c = 0; c < CDIM; ++c) { float t = xfw[c]; a = a + t * t; }
      sqfw = a;
    }
    float dw0 = 0.0f, dw1 = 0.0f;
#pragma unroll
    for (int c = 0; c < CDIM; ++c) {
      dw0 = __builtin_fmaf(xfw[c], xr0[c], dw0);
      dw1 = __builtin_fmaf(xfw[c], xr1[c], dw1);
    }
    CERTAIN_TAIL(sqfw, dw0, dw1, w)
    unsigned long long kA = key_of(df0, j0t);
    unsigned long long kB = (tid < TAILN) ? key_of(df1, j1t) : 0ull;
    KPair pp{kmax(kA, kB), kmin(kA, kB)};
    ExRes r = do_exchange(seg, row, pp, pp.b, sub, tid, lane, wid, wk, wb, wsec, res);
    ++row;
    int far1 = key_idx(r.g1);
    if (sub == 0 && wid == 1) {         // output row 1
      if (lane == 0) sidx[b * KSEL + 1] = (float)(far1 + td * NPTS);
      if (lane < 32) patches[(size_t)(b * KSEL + 1) * 32 + lane] =
                         xg[(size_t)far1 * CDIM + lane];
    }
    w = far1; cK = r.g2; cidx = key_idx(r.g2);
  }

  // ---- 63 pairs: steps (2,3), (4,5), ..., (126,127) ----
  for (int s = 2; s <= 126; s += 2) {
    // load both centers (overlapped L2-hit loads) + sqf chains
    const int wu = __builtin_amdgcn_readfirstlane(w);
    const int cu = __builtin_amdgcn_readfirstlane(cidx);
    const float* fw = xg + (size_t)wu * CDIM;
    const float* fc = xg + (size_t)cu * CDIM;
    float xfw[CDIM], xfc[CDIM];
#pragma unroll
    for (int c = 0; c < CDIM; ++c) { xfw[c] = fw[c]; xfc[c] = fc[c]; }
    float sqfw, sqfc;
    {
#pragma clang fp contract(off)
      float a = 0.0f;
#pragma unroll
      for (int c = 0; c < CDIM; ++c) { float t = xfw[c]; a = a + t * t; }
      sqfw = a;
      float e = 0.0f;
#pragma unroll
      for (int c = 0; c < CDIM; ++c) { float t = xfc[c]; e = e + t * t; }
      sqfc = e;
    }
    // 4 independent dot chains (ILP)
    float dw0 = 0.0f, dw1 = 0.0f, dc0 = 0.0f, dc1 = 0.0f;
#pragma unroll
    for (int c = 0; c < CDIM; ++c) {
      dw0 = __builtin_fmaf(xfw[c], xr0[c], dw0);
      dc0 = __builtin_fmaf(xfc[c], xr0[c], dc0);
      dw1 = __builtin_fmaf(xfw[c], xr1[c], dw1);
      dc1 = __builtin_fmaf(xfc[c], xr1[c], dc1);
    }
    // certain pass (center w) -> committed df, top-1 key
    CERTAIN_TAIL(sqfw, dw0, dw1, w)
    unsigned long long kk = key_of(df0, j0t);
    if (tid < TAILN) kk = kmax(kk, key_of(df1, j1t));
    // speculative pass (center c) on TOP of committed df -> dfs, top-2
    float dfs0 = df0, dfs1 = df1;
    {
      float d2a;
      { _Pragma("clang fp contract(off)") d2a = (sqfc + sqr0) - 2.0f * dc0; }
      d2a = fmaxf(d2a, 0.0f);
      float da = __fsqrt_rn(d2a);
      da = (j0t == cidx) ? -1.0f : da;
      dfs0 = fminf(da, df0);
      if (tid < TAILN) {
        float d2b;
        { _Pragma("clang fp contract(off)") d2b = (sqfc + sqr1) - 2.0f * dc1; }
        d2b = fmaxf(d2b, 0.0f);
        float db = __fsqrt_rn(d2b);
        db = (j1t == cidx) ? -1.0f : db;
        dfs1 = fminf(db, df1);
      }
    }
    unsigned long long kA = key_of(dfs0, j0t);
    unsigned long long kB = (tid < TAILN) ? key_of(dfs1, j1t) : 0ull;
    KPair pp{kmax(kA, kB), kmin(kA, kB)};

    ExRes r = do_exchange(seg, row, pp, kk, sub, tid, lane, wid, wk, wb, wsec, res);
    ++row;
    int farS = key_idx(r.maxkc);
    if (sub == 0 && wid == 1) {          // output row s
      if (lane == 0) sidx[b * KSEL + s] = (float)(farS + td * NPTS);
      if (lane < 32) patches[(size_t)(b * KSEL + s) * 32 + lane] =
                         xg[(size_t)farS * CDIM + lane];
    }

    if (r.maxkc == cK) {
      // speculation exact: dfs == S_{s+1}; commit and take 2nd step free
      df0 = dfs0; df1 = dfs1;
      int farS1 = key_idx(r.g1);
      if (sub == 0 && wid == 1) {        // output row s+1
        if (lane == 0) sidx[b * KSEL + s + 1] = (float)(farS1 + td * NPTS);
        if (lane < 32) patches[(size_t)(b * KSEL + s + 1) * 32 + lane] =
                           xg[(size_t)farS1 * CDIM + lane];
      }
      w = farS1; cK = r.g2; cidx = key_idx(r.g2);
    } else {
      // rollback (df untouched by spec) + normal exchange with true far_s
      const int eu = __builtin_amdgcn_readfirstlane(farS);
      const float* fe = xg + (size_t)eu * CDIM;
      float xfe[CDIM];
#pragma unroll
      for (int c = 0; c < CDIM; ++c) xfe[c] = fe[c];
      float sqfe;
      {
#pragma clang fp contract(off)
        float a = 0.0f;
#pragma unroll
        for (int c = 0; c < CDIM; ++c) { float t = xfe[c]; a = a + t * t; }
        sqfe = a;
      }
      float de0 = 0.0f, de1 = 0.0f;
#pragma unroll
      for (int c = 0; c < CDIM; ++c) {
        de0 = __builtin_fmaf(xfe[c], xr0[c], de0);
        de1 = __builtin_fmaf(xfe[c], xr1[c], de1);
      }
      CERTAIN_TAIL(sqfe, de0, de1, farS)
      unsigned long long kA2 = key_of(df0, j0t);
      unsigned long long kB2 = (tid < TAILN) ? key_of(df1, j1t) : 0ull;
      KPair pp2{kmax(kA2, kB2), kmin(kA2, kB2)};
      ExRes r2 = do_exchange(seg, row, pp2, pp2.b, sub, tid, lane, wid, wk, wb, wsec, res);
      ++row;
      int farS1 = key_idx(r2.g1);
      if (sub == 0 && wid == 1) {        // output row s+1
        if (lane == 0) sidx[b * KSEL + s + 1] = (float)(farS1 + td * NPTS);
        if (lane < 32) patches[(size_t)(b * KSEL + s + 1) * 32 + lane] =
                           xg[(size_t)farS1 * CDIM + lane];
      }
      w = farS1; cK = r2.g2; cidx = key_idx(r2.g2);
    }
  }
#undef CERTAIN_TAIL
}

extern "C" void kernel_launch(void* const* d_in, const int* in_sizes, int n_in,
                              void* d_out, int out_size, void* d_ws, size_t ws_size,
                              hipStream_t stream) {
  const float* x    = (const float*)d_in[0];
  const int*   init = (const int*)d_in[1];
  (void)in_sizes; (void)n_in; (void)out_size; (void)ws_size;

  // ws layout: slots [BT][ROWS][16 subs × 4 u64] = 8*128*64*8 = 512 KiB
  unsigned long long* slots = (unsigned long long*)d_ws;
  const size_t slots_bytes = (size_t)BT * ROWS * 64 * sizeof(unsigned long long);

  float* patches = (float*)d_out;
  float* sidx    = patches + (size_t)4 * 256 * 32;

  hipMemsetAsync(d_ws, 0, slots_bytes, stream);   // zero slot rows per launch

  void* kargs[] = { (void*)&x, (void*)&init, (void*)&patches, (void*)&sidx,
                    (void*)&slots };
  hipLaunchCooperativeKernel((const void*)fps_kernel, dim3(NB), dim3(BLK),
                             kargs, 0, stream);
}